// Round 3
// baseline (610.903 us; speedup 1.0000x reference)
//
#include <hip/hip_runtime.h>
#include <hip/hip_bf16.h>

typedef short short8 __attribute__((ext_vector_type(8)));
typedef float float4v __attribute__((ext_vector_type(4)));

#define MFMA(a, b, c) __builtin_amdgcn_mfma_f32_16x16x32_bf16((a), (b), (c), 0, 0, 0)

typedef const __attribute__((address_space(1))) unsigned int gu32;
typedef __attribute__((address_space(3))) unsigned int lu32;
#define GLOAD_LDS16(g, l) __builtin_amdgcn_global_load_lds((gu32*)(g), (lu32*)(l), 16, 0, 0)

static __device__ __forceinline__ unsigned short f2bf(float f) {
    union { float f; unsigned u; } v; v.f = f;
    unsigned r = (v.u + 0x7fffu + ((v.u >> 16) & 1u)) >> 16;
    return (unsigned short)r;
}
static __device__ __forceinline__ float bf2f(unsigned short h) {
    union { unsigned u; float f; } v; v.u = ((unsigned)h) << 16;
    return v.f;
}

// Fragment-blocked layouts: each MFMA fragment (16 rows x 32 k-elems) is 1024
// contiguous bytes, ordered so lane i's 16B piece sits at offset i*16.
//   q/k: (b, n, o)  frag = (b*512 + n/16)*2 + o/32
static __device__ __forceinline__ int qk_idx(int b, int n, int o) {
    int frag = (b * 512 + (n >> 4)) * 2 + (o >> 5);
    return frag * 512 + ((o >> 3) & 3) * 128 + (n & 15) * 8 + (o & 7);
}
//   v: (b, c, n)  frag = (b*256 + n/32)*16 + c/16
static __device__ __forceinline__ int v_idx(int b, int c, int n) {
    int frag = (b * 256 + (n >> 5)) * 16 + (c >> 4);
    return frag * 512 + ((n >> 3) & 3) * 128 + (c & 15) * 8 + (n & 7);
}

// ---------------------------------------------------------------------------
// Kernel 0: weights fp32 -> bf16 (hi for all; lo for Wq/Wk split-bf16 path)
// ---------------------------------------------------------------------------
__global__ void wcvt(const float* __restrict__ Wq, const float* __restrict__ Wk,
                     const float* __restrict__ Wv,
                     unsigned short* __restrict__ Whi, unsigned short* __restrict__ Wlo) {
    int idx = blockIdx.x * 256 + threadIdx.x;
    if (idx >= 384 * 256) return;
    int row = idx >> 8, c = idx & 255;
    float f;
    if (row < 64)       f = Wq[row * 256 + c];
    else if (row < 128) f = Wk[(row - 64) * 256 + c];
    else                f = Wv[(row - 128) * 256 + c];
    unsigned short hi = f2bf(f);
    Whi[idx] = hi;
    if (row < 128) Wlo[idx] = f2bf(f - bf2f(hi));
}

// ---------------------------------------------------------------------------
// Kernel 1: projections -> fragment-blocked q(hi/lo), k(hi/lo), v outputs.
// ---------------------------------------------------------------------------
__global__ __launch_bounds__(256, 1) void proj(
        const float* __restrict__ x, const unsigned short* __restrict__ Whi,
        const unsigned short* __restrict__ Wlo,
        const float* __restrict__ bq, const float* __restrict__ bk,
        const float* __restrict__ bv,
        unsigned short* __restrict__ qhi_ws, unsigned short* __restrict__ qlo_ws,
        unsigned short* __restrict__ khi_ws, unsigned short* __restrict__ klo_ws,
        unsigned short* __restrict__ vws) {
    __shared__ unsigned short XThi[64 * 264];  // [n][c] bf16 hi, pitch 264
    __shared__ unsigned short XTlo[64 * 264];  // [n][c] bf16 lo

    const int tid = threadIdx.x;
    const int b  = blockIdx.x >> 7;
    const int n0 = (blockIdx.x & 127) << 6;
    const float* xb = x + b * 2097152;  // [256][8192]

    for (int p = 0; p < 16; ++p) {
        int idx = p * 256 + tid;
        int c = idx >> 4, nq = idx & 15;
        float4v xv = *reinterpret_cast<const float4v*>(xb + c * 8192 + n0 + nq * 4);
#pragma unroll
        for (int q = 0; q < 4; ++q) {
            unsigned short hi = f2bf(xv[q]);
            XThi[(nq * 4 + q) * 264 + c] = hi;
            XTlo[(nq * 4 + q) * 264 + c] = f2bf(xv[q] - bf2f(hi));
        }
    }
    __syncthreads();

    const int lane = tid & 63, w = tid >> 6;
    const int quad = lane >> 4, l16 = lane & 15;

    // ---- GEMM1: q,k (split-bf16, 3 terms) ----
    short8 aXhi[8], aXlo[8];
#pragma unroll
    for (int ks = 0; ks < 8; ++ks) {
        aXhi[ks] = *reinterpret_cast<const short8*>(&XThi[(w * 16 + l16) * 264 + ks * 32 + quad * 8]);
        aXlo[ks] = *reinterpret_cast<const short8*>(&XTlo[(w * 16 + l16) * 264 + ks * 32 + quad * 8]);
    }

#pragma unroll
    for (int ot = 0; ot < 8; ++ot) {
        float4v acc = {0.f, 0.f, 0.f, 0.f};
#pragma unroll
        for (int ks = 0; ks < 8; ++ks) {
            short8 bwhi = *reinterpret_cast<const short8*>(&Whi[(ot * 16 + l16) * 256 + ks * 32 + quad * 8]);
            short8 bwlo = *reinterpret_cast<const short8*>(&Wlo[(ot * 16 + l16) * 256 + ks * 32 + quad * 8]);
            acc = MFMA(aXhi[ks], bwhi, acc);
            acc = MFMA(aXlo[ks], bwhi, acc);
            acc = MFMA(aXhi[ks], bwlo, acc);
        }
        int o = ot * 16 + l16;
        float bias = (ot < 4) ? bq[o] : bk[o - 64];
#pragma unroll
        for (int r = 0; r < 4; ++r) {
            int n = n0 + w * 16 + quad * 4 + r;
            float y = acc[r] + bias;
            unsigned short hi = f2bf(y);
            unsigned short lo = f2bf(y - bf2f(hi));
            if (ot < 4) {
                int id = qk_idx(b, n, o);
                qhi_ws[id] = hi; qlo_ws[id] = lo;
            } else {
                int id = qk_idx(b, n, o - 64);
                khi_ws[id] = hi; klo_ws[id] = lo;
            }
        }
    }

    // ---- GEMM2: V[c][n] (single bf16) ----
    float4v acc2[4][4];
#pragma unroll
    for (int mt = 0; mt < 4; ++mt)
#pragma unroll
        for (int nt = 0; nt < 4; ++nt) acc2[mt][nt] = (float4v){0.f, 0.f, 0.f, 0.f};

#pragma unroll
    for (int ks = 0; ks < 8; ++ks) {
        short8 aW[4], bX[4];
#pragma unroll
        for (int mt = 0; mt < 4; ++mt)
            aW[mt] = *reinterpret_cast<const short8*>(&Whi[(128 + w * 64 + mt * 16 + l16) * 256 + ks * 32 + quad * 8]);
#pragma unroll
        for (int nt = 0; nt < 4; ++nt)
            bX[nt] = *reinterpret_cast<const short8*>(&XThi[(nt * 16 + l16) * 264 + ks * 32 + quad * 8]);
#pragma unroll
        for (int mt = 0; mt < 4; ++mt)
#pragma unroll
            for (int nt = 0; nt < 4; ++nt)
                acc2[mt][nt] = MFMA(aW[mt], bX[nt], acc2[mt][nt]);
    }
#pragma unroll
    for (int mt = 0; mt < 4; ++mt) {
#pragma unroll
        for (int r = 0; r < 4; ++r) {
            int c = w * 64 + mt * 16 + quad * 4 + r;
            float bias = bv[c];
#pragma unroll
            for (int nt = 0; nt < 4; ++nt) {
                int n = n0 + nt * 16 + l16;
                vws[v_idx(b, c, n)] = f2bf(acc2[mt][nt][r] + bias);
            }
        }
    }
}

// ---------------------------------------------------------------------------
// Kernel 2: flash attention + residual. 1 barrier/iteration.
//   K: LDS double-buffer via async global_load_lds (width 16).
//   V: global -> B-frag registers directly (fragment-blocked layout).
//   P, alpha: LDS double-buffered.
// ---------------------------------------------------------------------------
__global__ __launch_bounds__(256, 1) void attn(
        const unsigned short* __restrict__ qhi_ws, const unsigned short* __restrict__ qlo_ws,
        const unsigned short* __restrict__ khi_ws, const unsigned short* __restrict__ klo_ws,
        const unsigned short* __restrict__ vws, const float* __restrict__ x,
        float* __restrict__ out) {
    __shared__ unsigned short Klds[2][2][4096];  // [buf][hi/lo][frag-blocked 8KB]
    __shared__ unsigned short Plds[2][64 * 72];  // [buf][i][j] padded
    __shared__ float alpha_lds[2][64];
    __shared__ float l_lds[64];

    const int tid = threadIdx.x;
    const int b  = blockIdx.x >> 7;
    const int i0 = (blockIdx.x & 127) << 6;
    const int lane = tid & 63, w = tid >> 6;
    const int quad = lane >> 4, l16 = lane & 15;

    // Q fragments (wave owns rows i0 + w*16 .. +16)
    short8 qfh[2], qfl[2];
#pragma unroll
    for (int ks = 0; ks < 2; ++ks) {
        int frag = (b * 512 + (i0 >> 4) + w) * 2 + ks;
        qfh[ks] = *reinterpret_cast<const short8*>(qhi_ws + frag * 512 + lane * 8);
        qfl[ks] = *reinterpret_cast<const short8*>(qlo_ws + frag * 512 + lane * 8);
    }

    float4v acc[4][4];
#pragma unroll
    for (int mt = 0; mt < 4; ++mt)
#pragma unroll
        for (int ct = 0; ct < 4; ++ct) acc[mt][ct] = (float4v){0.f, 0.f, 0.f, 0.f};
    float mrow[4] = {-1e30f, -1e30f, -1e30f, -1e30f};
    float lrow[4] = {0.f, 0.f, 0.f, 0.f};

    // Preload K tile 0 (16 chunks of 1KB; wave w takes chunks 4w..4w+3)
#pragma unroll
    for (int q = 0; q < 4; ++q) {
        int ch = w * 4 + q;
        int hl = ch >> 3, rem = ch & 7, jtl = rem >> 1, ks = rem & 1;
        int frag = (b * 512 + jtl) * 2 + ks;
        const unsigned short* sp = (hl ? klo_ws : khi_ws) + frag * 512 + lane * 8;
        GLOAD_LDS16(sp, &Klds[0][hl][(jtl * 2 + ks) * 512 + lane * 8]);
    }
    __syncthreads();

    int kbuf = 0, pbuf = 0;
    for (int it = 0; it < 128; ++it) {
        // ---- V fragments for tile it: straight to registers ----
        short8 vf[2][4];
#pragma unroll
        for (int half = 0; half < 2; ++half)
#pragma unroll
            for (int ct = 0; ct < 4; ++ct) {
                int frag = (b * 256 + it * 2 + half) * 16 + w * 4 + ct;
                vf[half][ct] = *reinterpret_cast<const short8*>(vws + frag * 512 + lane * 8);
            }

        // ---- async prefetch K[it+1] into the other LDS buffer ----
        if (it < 127) {
#pragma unroll
            for (int q = 0; q < 4; ++q) {
                int ch = w * 4 + q;
                int hl = ch >> 3, rem = ch & 7, jtl = rem >> 1, ks = rem & 1;
                int frag = (b * 512 + (it + 1) * 4 + jtl) * 2 + ks;
                const unsigned short* sp = (hl ? klo_ws : khi_ws) + frag * 512 + lane * 8;
                GLOAD_LDS16(sp, &Klds[kbuf ^ 1][hl][(jtl * 2 + ks) * 512 + lane * 8]);
            }
        }

        // ---- QK^T (split-bf16): wave computes S[16 own rows][64 j] ----
        float4v s[4];
#pragma unroll
        for (int jt = 0; jt < 4; ++jt) s[jt] = (float4v){0.f, 0.f, 0.f, 0.f};
#pragma unroll
        for (int ks = 0; ks < 2; ++ks)
#pragma unroll
            for (int jt = 0; jt < 4; ++jt) {
                short8 bkh = *reinterpret_cast<const short8*>(&Klds[kbuf][0][(jt * 2 + ks) * 512 + lane * 8]);
                short8 bkl = *reinterpret_cast<const short8*>(&Klds[kbuf][1][(jt * 2 + ks) * 512 + lane * 8]);
                s[jt] = MFMA(qfh[ks], bkh, s[jt]);
                s[jt] = MFMA(qfl[ks], bkh, s[jt]);
                s[jt] = MFMA(qfh[ks], bkl, s[jt]);
            }

        // ---- online softmax ----
#pragma unroll
        for (int r = 0; r < 4; ++r) {
            float mx = fmaxf(fmaxf(s[0][r], s[1][r]), fmaxf(s[2][r], s[3][r]));
            mx = fmaxf(mx, __shfl_xor(mx, 1));
            mx = fmaxf(mx, __shfl_xor(mx, 2));
            mx = fmaxf(mx, __shfl_xor(mx, 4));
            mx = fmaxf(mx, __shfl_xor(mx, 8));
            float mn = fmaxf(mrow[r], mx);
            float al = __expf(mrow[r] - mn);
            mrow[r] = mn;
            float rs = 0.f;
#pragma unroll
            for (int jt = 0; jt < 4; ++jt) {
                float p_ = __expf(s[jt][r] - mn);
                unsigned short pb = f2bf(p_);
                rs += bf2f(pb);  // same rounded weights PV uses
                Plds[pbuf][(w * 16 + quad * 4 + r) * 72 + jt * 16 + l16] = pb;
            }
            lrow[r] = al * lrow[r] + rs;
            if (l16 == 0) alpha_lds[pbuf][w * 16 + quad * 4 + r] = al;
        }
        __syncthreads();  // P/alpha visible; drains V loads + K[it+1] async

        // ---- rescale O, then PV (wave owns c in [64w, 64w+64)) ----
        short8 aP[4][2];
#pragma unroll
        for (int mt = 0; mt < 4; ++mt)
#pragma unroll
            for (int ks = 0; ks < 2; ++ks)
                aP[mt][ks] = *reinterpret_cast<const short8*>(&Plds[pbuf][(mt * 16 + l16) * 72 + ks * 32 + quad * 8]);
#pragma unroll
        for (int mt = 0; mt < 4; ++mt) {
            float av[4];
#pragma unroll
            for (int r = 0; r < 4; ++r) av[r] = alpha_lds[pbuf][mt * 16 + quad * 4 + r];
#pragma unroll
            for (int ct = 0; ct < 4; ++ct)
#pragma unroll
                for (int r = 0; r < 4; ++r) acc[mt][ct][r] *= av[r];
        }
#pragma unroll
        for (int ct = 0; ct < 4; ++ct) {
#pragma unroll
            for (int mt = 0; mt < 4; ++mt) acc[mt][ct] = MFMA(aP[mt][0], vf[0][ct], acc[mt][ct]);
#pragma unroll
            for (int mt = 0; mt < 4; ++mt) acc[mt][ct] = MFMA(aP[mt][1], vf[1][ct], acc[mt][ct]);
        }

        kbuf ^= 1; pbuf ^= 1;
    }

    // ---- final l reduction ----
#pragma unroll
    for (int r = 0; r < 4; ++r) {
        float lv = lrow[r];
        lv += __shfl_xor(lv, 1);
        lv += __shfl_xor(lv, 2);
        lv += __shfl_xor(lv, 4);
        lv += __shfl_xor(lv, 8);
        if (l16 == 0) l_lds[w * 16 + quad * 4 + r] = lv;
    }
    __syncthreads();

    // ---- epilogue: O/l + x via per-wave LDS transpose (Plds reused fp32) ----
    const float linv = 1.0f / l_lds[lane];
    float* ep = reinterpret_cast<float*>(&Plds[0][0]) + w * (16 * 68);
    const float* xb2 = x + b * 2097152;
    float* ob = out + b * 2097152;
#pragma unroll 1
    for (int ct = 0; ct < 4; ++ct) {
#pragma unroll
        for (int mt = 0; mt < 4; ++mt)
#pragma unroll
            for (int r = 0; r < 4; ++r)
                ep[l16 * 68 + mt * 16 + quad * 4 + r] = acc[mt][ct][r];
        __syncthreads();
#pragma unroll 1
        for (int rr = 0; rr < 16; ++rr) {
            int c = (w << 6) + ct * 16 + rr;
            float o = ep[rr * 68 + lane] * linv;
            float xv = xb2[c * 8192 + i0 + lane];
            ob[c * 8192 + i0 + lane] = o + xv;
        }
        __syncthreads();
    }
}

// ---------------------------------------------------------------------------
extern "C" void kernel_launch(void* const* d_in, const int* in_sizes, int n_in,
                              void* d_out, int out_size, void* d_ws, size_t ws_size,
                              hipStream_t stream) {
    const float* x  = (const float*)d_in[0];
    const float* Wq = (const float*)d_in[1];
    const float* bq = (const float*)d_in[2];
    const float* Wk = (const float*)d_in[3];
    const float* bk = (const float*)d_in[4];
    const float* Wv = (const float*)d_in[5];
    const float* bv = (const float*)d_in[6];

    unsigned short* Whi = (unsigned short*)d_ws;           // 384*256
    unsigned short* Wlo = Whi + 384 * 256;                 // 128*256
    unsigned short* qhi = Wlo + 128 * 256;                 // [2][8192][64] blocked
    unsigned short* qlo = qhi + 2 * 8192 * 64;
    unsigned short* khi = qlo + 2 * 8192 * 64;
    unsigned short* klo = khi + 2 * 8192 * 64;
    unsigned short* vws = klo + 2 * 8192 * 64;             // [2][256][8192] blocked

    wcvt<<<384, 256, 0, stream>>>(Wq, Wk, Wv, Whi, Wlo);
    proj<<<256, 256, 0, stream>>>(x, Whi, Wlo, bq, bk, bv, qhi, qlo, khi, klo, vws);
    attn<<<256, 256, 0, stream>>>(qhi, qlo, khi, klo, vws, x, (float*)d_out);
}